// Round 13
// baseline (198.098 us; speedup 1.0000x reference)
//
#include <hip/hip_runtime.h>

#define DI __device__ __forceinline__

constexpr int B_ = 16;
constexpr int C_ = 512;
constexpr int W_ = 2048;
constexpr int C4 = 128;
constexpr int C2 = 256;
constexpr int Q_ = 1024;

typedef short bf16x8 __attribute__((ext_vector_type(8)));
typedef float f32x4 __attribute__((ext_vector_type(4)));

DI f32x4 MFMA(bf16x8 a, bf16x8 b, f32x4 c) {
  return __builtin_amdgcn_mfma_f32_16x16x32_bf16(a, b, c, 0, 0, 0);
}

DI unsigned short f2bf(float v) {
  union { float f; unsigned int i; } c; c.f = v;
  return (unsigned short)((c.i + 0x7FFFu + ((c.i >> 16) & 1u)) >> 16);
}

DI float bf16_to_f(unsigned short u) {
  union { unsigned int i; float f; } c; c.i = ((unsigned int)u) << 16; return c.f;
}

DI bf16x8 ldfrag(const unsigned short* p, int ld) {
  const int l = threadIdx.x & 63;
  return *(const bf16x8*)(p + (size_t)(l & 15) * ld + ((l >> 4) << 3));
}

// async 16B global->LDS; lds dest is wave-uniform base + lane*16
DI void gload16(const unsigned short* g, unsigned short* l) {
  __builtin_amdgcn_global_load_lds((const __attribute__((address_space(1))) void*)(g),
                                   (__attribute__((address_space(3))) void*)(l), 16, 0, 0);
}

// ---------------------------------------------------------------------------
// Prep 1: weights -> bf16.  [wf 64K][wg 64K][wh 128K][wa 128K]
// ---------------------------------------------------------------------------
__global__ __launch_bounds__(256)
void k_cvt(const float* __restrict__ wf, const float* __restrict__ wg,
           const float* __restrict__ wh, const float* __restrict__ wa,
           unsigned short* __restrict__ dst)
{
  const int i = blockIdx.x * 256 + threadIdx.x;
  float v;
  if (i < 65536)        v = wf[i];
  else if (i < 131072)  v = wg[i - 65536];
  else if (i < 262144)  v = wh[i - 131072];
  else                  v = wa[i - 262144];
  dst[i] = f2bf(v);
}

// ---------------------------------------------------------------------------
// Prep 2: xT[b][w][c] bf16 = transpose of x[b][c][w] f32.
// ---------------------------------------------------------------------------
__global__ __launch_bounds__(256)
void k_tx(const float* __restrict__ x, unsigned short* __restrict__ xT)
{
  __shared__ float tile[64][68];
  const int b = blockIdx.z, c0 = blockIdx.y * 64, w0 = blockIdx.x * 64;
  const int t = threadIdx.x;
  #pragma unroll
  for (int p = 0; p < 4; ++p) {
    const int r = p * 16 + (t >> 4);
    const float4 v = *(const float4*)&x[((size_t)(b * C_ + c0 + r)) * W_ + w0 + (t & 15) * 4];
    *(float4*)&tile[r][(t & 15) * 4] = v;
  }
  __syncthreads();
  const int w = t >> 2, ch = (t & 3) * 16;
  unsigned short o[16];
  #pragma unroll
  for (int j = 0; j < 16; ++j) o[j] = f2bf(tile[ch + j][w]);
  unsigned short* dst = &xT[((size_t)(b * W_ + w0 + w)) * C_ + c0 + ch];
  *(uint4*)&dst[0] = *(uint4*)&o[0];
  *(uint4*)&dst[8] = *(uint4*)&o[8];
}

// ---------------------------------------------------------------------------
// K1: m97-style LDS-staged GEMM, conflict-free XOR-swizzled staging.
// Tile 128(w) x 128(ch), BK=32, 4 waves 2x2. grid (16,4,16)
// ---------------------------------------------------------------------------
__global__ __launch_bounds__(256)
void k_fgh(const unsigned short* __restrict__ xT, const unsigned short* __restrict__ wcat,
           const float* __restrict__ bfp, const float* __restrict__ bgp,
           const float* __restrict__ bhp,
           unsigned short* __restrict__ fT, unsigned short* __restrict__ gT,
           unsigned short* __restrict__ h)
{
  const int b = blockIdx.z, rt = blockIdx.y, w0 = blockIdx.x * 128;
  const int t = threadIdx.x, l = t & 63, wv = t >> 6;
  const int wr = wv >> 1, wc = wv & 1;

  __shared__ __align__(16) char smraw[33792];   // staging 32KB | epilogue 64x132 f32
  unsigned short* stg = (unsigned short*)smraw; // [buf][ab][4096]
  float (*eps)[132] = (float(*)[132])smraw;

  const unsigned short* Abase = xT + ((size_t)(b * W_ + w0)) * C_;
  const unsigned short* Bbase = wcat + (size_t)(rt * 128) * C_;

  const int wub = (t & 192) * 8;
  const int r0s = t >> 2;
  // swizzled source granule: g' = g ^ ((row>>1)&3); row = i*64 + (t>>2)
  const int kcs = ((t & 3) ^ ((t >> 3) & 3)) * 8;
  // swizzled read offset (per-lane constant; row&15 = l&15)
  const int gsw = (((l >> 4) ^ ((l >> 1) & 3)) << 3);

  auto STAGE = [&](int buf, int c0) {
    #pragma unroll
    for (int i = 0; i < 2; ++i) {
      const int row = i * 64 + r0s;
      gload16(Abase + (size_t)row * C_ + c0 + kcs, stg + (buf * 2 + 0) * 4096 + i * 2048 + wub);
      gload16(Bbase + (size_t)row * C_ + c0 + kcs, stg + (buf * 2 + 1) * 4096 + i * 2048 + wub);
    }
  };

  f32x4 acc[4][4];
  #pragma unroll
  for (int i = 0; i < 4; ++i)
    #pragma unroll
    for (int j = 0; j < 4; ++j) acc[i][j] = (f32x4){0.f, 0.f, 0.f, 0.f};

  STAGE(0, 0);
  for (int kt = 0; kt < 16; ++kt) {
    const int cur = kt & 1;
    __syncthreads();
    if (kt + 1 < 16) STAGE(cur ^ 1, (kt + 1) * 32);
    const unsigned short* As = stg + (cur * 2 + 0) * 4096;
    const unsigned short* Bs = stg + (cur * 2 + 1) * 4096;
    bf16x8 a[4], bb[4];
    #pragma unroll
    for (int i = 0; i < 4; ++i)
      a[i] = *(const bf16x8*)&As[(wr * 64 + i * 16 + (l & 15)) * 32 + gsw];
    #pragma unroll
    for (int j = 0; j < 4; ++j)
      bb[j] = *(const bf16x8*)&Bs[(wc * 64 + j * 16 + (l & 15)) * 32 + gsw];
    #pragma unroll
    for (int i = 0; i < 4; ++i)
      #pragma unroll
      for (int j = 0; j < 4; ++j)
        acc[i][j] = MFMA(a[i], bb[j], acc[i][j]);
  }
  __syncthreads();

  const int lr = l >> 4, lc = l & 15;

  if (rt == 1) {
    #pragma unroll
    for (int p = 0; p < 2; ++p) {
      if (p) __syncthreads();
      if (wr == p) {
        #pragma unroll
        for (int i = 0; i < 4; ++i)
          #pragma unroll
          for (int j = 0; j < 4; ++j)
            #pragma unroll
            for (int r = 0; r < 4; ++r)
              eps[i * 16 + lr * 4 + r][wc * 64 + j * 16 + lc] = acc[i][j][r];
      }
      __syncthreads();
      const int row = t >> 2, chunk = (t & 3) * 32;
      unsigned short o[32];
      #pragma unroll
      for (int j2 = 0; j2 < 32; ++j2) o[j2] = f2bf(eps[row][chunk + j2] + bgp[chunk + j2]);
      unsigned short* dst = &gT[((size_t)(b * W_ + w0 + p * 64 + row)) * C4 + chunk];
      #pragma unroll
      for (int u = 0; u < 4; ++u) *(uint4*)&dst[u * 8] = *(uint4*)&o[u * 8];
    }
  } else {
    #pragma unroll
    for (int i = 0; i < 4; ++i)
      #pragma unroll
      for (int j = 0; j < 4; ++j)
        #pragma unroll
        for (int jj = 0; jj < 2; ++jj)
          eps[wr * 32 + i * 8 + lr * 2 + jj][wc * 64 + j * 16 + lc] =
              fmaxf(acc[i][j][2 * jj], acc[i][j][2 * jj + 1]);
    __syncthreads();
    if (rt == 0) {
      const int row = t >> 2, chunk = (t & 3) * 32;
      unsigned short o[32];
      #pragma unroll
      for (int j2 = 0; j2 < 32; ++j2) o[j2] = f2bf(eps[row][chunk + j2] + bfp[chunk + j2]);
      unsigned short* dst = &fT[((size_t)(b * Q_ + (w0 >> 1) + row)) * C4 + chunk];
      #pragma unroll
      for (int u = 0; u < 4; ++u) *(uint4*)&dst[u * 8] = *(uint4*)&o[u * 8];
    } else {
      const int ch = t >> 1, half = (t & 1) * 32;
      const float bv = bhp[(rt - 2) * 128 + ch];
      unsigned short o[32];
      #pragma unroll
      for (int qq = 0; qq < 32; ++qq) o[qq] = f2bf(eps[half + qq][ch] + bv);
      unsigned short* dst = &h[((size_t)(b * C2 + (rt - 2) * 128 + ch)) * Q_ + (w0 >> 1) + half];
      #pragma unroll
      for (int u = 0; u < 4; ++u) *(uint4*)&dst[u * 8] = *(uint4*)&o[u * 8];
    }
  }
}

// ---------------------------------------------------------------------------
// K2a: k_stats — lpart[kt][b][q] = sum over this k-tile of exp(s[q,k]).
// Conflict-free swizzled staging. grid (16,8,16)
// ---------------------------------------------------------------------------
__global__ __launch_bounds__(256)
void k_stats(const unsigned short* __restrict__ fT, const unsigned short* __restrict__ gT,
             float* __restrict__ lpart)
{
  const int kt = blockIdx.x, qt = blockIdx.y, b = blockIdx.z;
  const int t = threadIdx.x, l = t & 63, wv = t >> 6;
  const int wr = wv >> 1, wc = wv & 1;

  __shared__ __align__(16) char smraw[33792];
  unsigned short* stg = (unsigned short*)smraw;
  float* sred = (float*)smraw;

  const unsigned short* Abase = fT + ((size_t)(b * Q_ + qt * 128)) * C4;
  const unsigned short* Bbase = gT + ((size_t)(b * W_ + kt * 128)) * C4;

  const int wub = (t & 192) * 8;
  const int r0s = t >> 2;
  const int kcs = ((t & 3) ^ ((t >> 3) & 3)) * 8;
  const int gsw = (((l >> 4) ^ ((l >> 1) & 3)) << 3);

  auto STAGE = [&](int buf, int c0) {
    #pragma unroll
    for (int i = 0; i < 2; ++i) {
      const int row = i * 64 + r0s;
      gload16(Abase + (size_t)row * C4 + c0 + kcs, stg + (buf * 2 + 0) * 4096 + i * 2048 + wub);
      gload16(Bbase + (size_t)row * C4 + c0 + kcs, stg + (buf * 2 + 1) * 4096 + i * 2048 + wub);
    }
  };

  f32x4 acc[4][4];
  #pragma unroll
  for (int i = 0; i < 4; ++i)
    #pragma unroll
    for (int j = 0; j < 4; ++j) acc[i][j] = (f32x4){0.f, 0.f, 0.f, 0.f};

  STAGE(0, 0);
  for (int ks = 0; ks < 4; ++ks) {
    const int cur = ks & 1;
    __syncthreads();
    if (ks + 1 < 4) STAGE(cur ^ 1, (ks + 1) * 32);
    const unsigned short* As = stg + (cur * 2 + 0) * 4096;
    const unsigned short* Bs = stg + (cur * 2 + 1) * 4096;
    bf16x8 a[4], bb[4];
    #pragma unroll
    for (int i = 0; i < 4; ++i)
      a[i] = *(const bf16x8*)&As[(wr * 64 + i * 16 + (l & 15)) * 32 + gsw];
    #pragma unroll
    for (int j = 0; j < 4; ++j)
      bb[j] = *(const bf16x8*)&Bs[(wc * 64 + j * 16 + (l & 15)) * 32 + gsw];
    #pragma unroll
    for (int i = 0; i < 4; ++i)
      #pragma unroll
      for (int j = 0; j < 4; ++j)
        acc[i][j] = MFMA(a[i], bb[j], acc[i][j]);
  }
  __syncthreads();

  const int lr = l >> 4, lc = l & 15;
  float sv[4][4];
  #pragma unroll
  for (int i = 0; i < 4; ++i)
    #pragma unroll
    for (int r = 0; r < 4; ++r) {
      float s = 0.f;
      #pragma unroll
      for (int j = 0; j < 4; ++j) s += __expf(acc[i][j][r]);
      #pragma unroll
      for (int d = 1; d < 16; d <<= 1) s += __shfl_xor(s, d);
      sv[i][r] = s;
    }
  if (lc == 0) {
    #pragma unroll
    for (int i = 0; i < 4; ++i)
      #pragma unroll
      for (int r = 0; r < 4; ++r)
        sred[wc * 128 + wr * 64 + i * 16 + lr * 4 + r] = sv[i][r];
  }
  __syncthreads();
  if (t < 128)
    lpart[((size_t)(kt * 16 + b)) * Q_ + qt * 128 + t] = sred[t] + sred[128 + t];
}

// ---------------------------------------------------------------------------
// K2b: k_hprime — h''[c][q] = h[c][q] / l[q], l = sum of 16 lpart slices.
// grid (Q/128, B), 256 thr
// ---------------------------------------------------------------------------
__global__ __launch_bounds__(256)
void k_hprime(const unsigned short* __restrict__ h, const float* __restrict__ lpart,
              unsigned short* __restrict__ hpp)
{
  const int qb = blockIdx.x, b = blockIdx.y;
  const int t = threadIdx.x;
  __shared__ float linv[128];
  if (t < 128) {
    float s = 0.f;
    #pragma unroll
    for (int kt = 0; kt < 16; ++kt)
      s += lpart[((size_t)(kt * 16 + b)) * Q_ + qb * 128 + t];
    linv[t] = 1.f / s;
  }
  __syncthreads();
  const int q8 = (t & 15) * 8;
  for (int it = 0; it < 16; ++it) {
    const int c = it * 16 + (t >> 4);
    const size_t off = ((size_t)(b * C2 + c)) * Q_ + qb * 128 + q8;
    const bf16x8 v = *(const bf16x8*)&h[off];
    unsigned short o[8];
    #pragma unroll
    for (int e = 0; e < 8; ++e)
      o[e] = f2bf(bf16_to_f((unsigned short)v[e]) * linv[q8 + e]);
    *(uint4*)&hpp[off] = *(uint4*)o;
  }
}

// ---------------------------------------------------------------------------
// K3f v2: fused o1T[k][c] = sum_q exp(sT[k][q]) * h''[c][q].
// c-SPLIT for 2 blocks/CU: block = 128k x 128c (cy half), grid (16, 2, 16).
// LDS 66KB: Gt 32KB + Fa (F 32KB / p 34KB overlay). PV B-frags direct from
// L2 (hpp L3-resident). No persistent A-frag hoist (VGPR <= 128).
// 512 thr, __launch_bounds__(512,4) -> 16 waves/CU.
// ---------------------------------------------------------------------------
__global__ __launch_bounds__(512, 4)
void k_o1f(const unsigned short* __restrict__ fT, const unsigned short* __restrict__ gT,
           const unsigned short* __restrict__ hpp, unsigned short* __restrict__ o1T)
{
  const int b = blockIdx.z, cy = blockIdx.y, k0 = blockIdx.x * 128;
  const int t = threadIdx.x, l = t & 63, wv = t >> 6;
  const int lcq = l & 15, lrq = l >> 4;

  __shared__ __align__(16) char smem[67584];
  unsigned short* Gt = (unsigned short*)smem;            // [128][128] 32 KB
  unsigned short* Fa = (unsigned short*)(smem + 32768);  // F [128][128] / p [128][136]

  // stage Gt once (swizzled source)
  #pragma unroll
  for (int rd = 0; rd < 4; ++rd) {
    const int idx = rd * 512 + t, row = idx >> 4, g = idx & 15;
    gload16(gT + ((size_t)(b * W_ + k0 + row)) * C4 + ((g ^ (row & 15)) << 3), Gt + idx * 8);
  }
  auto STAGE_F = [&](int qc) {
    #pragma unroll
    for (int rd = 0; rd < 4; ++rd) {
      const int idx = rd * 512 + t, row = idx >> 4, g = idx & 15;
      gload16(fT + ((size_t)(b * Q_ + qc * 128 + row)) * C4 + ((g ^ (row & 15)) << 3),
              Fa + idx * 8);
    }
  };
  STAGE_F(0);
  __syncthreads();

  const int koff = (wv >> 2) * 64;        // k offset (both phases)
  const int qoff = (wv & 3) * 32;         // s-phase q offset
  const int coff = (wv & 3) * 32;         // PV c offset (within this cy half)

  const unsigned short* Hbase = hpp + ((size_t)(b * C2 + cy * 128)) * Q_;

  f32x4 oac[4][2];
  #pragma unroll
  for (int i = 0; i < 4; ++i)
    #pragma unroll
    for (int j = 0; j < 2; ++j) oac[i][j] = (f32x4){0.f, 0.f, 0.f, 0.f};

  for (int qc = 0; qc < 8; ++qc) {
    // ---- s-phase: sT[k][q] over this chunk (wave: 64k x 32q) ----
    f32x4 sacc[4][2];
    #pragma unroll
    for (int i = 0; i < 4; ++i)
      #pragma unroll
      for (int j = 0; j < 2; ++j) sacc[i][j] = (f32x4){0.f, 0.f, 0.f, 0.f};
    #pragma unroll
    for (int cs = 0; cs < 4; ++cs) {
      bf16x8 ag[4], bq[2];
      #pragma unroll
      for (int i = 0; i < 4; ++i)
        ag[i] = *(const bf16x8*)
            &Gt[(koff + i * 16 + lcq) * 128 + (((cs * 4 + lrq) ^ lcq) << 3)];
      #pragma unroll
      for (int j = 0; j < 2; ++j)
        bq[j] = *(const bf16x8*)
            &Fa[(qoff + j * 16 + lcq) * 128 + (((cs * 4 + lrq) ^ lcq) << 3)];
      #pragma unroll
      for (int i = 0; i < 4; ++i)
        #pragma unroll
        for (int j = 0; j < 2; ++j)
          sacc[i][j] = MFMA(ag[i], bq[j], sacc[i][j]);
    }
    __syncthreads();                      // F reads done

    // ---- p = exp(sT) -> arena [128][136] bf16 ----
    #pragma unroll
    for (int i = 0; i < 4; ++i)
      #pragma unroll
      for (int j = 0; j < 2; ++j)
        #pragma unroll
        for (int r = 0; r < 4; ++r)
          Fa[(koff + i * 16 + lrq * 4 + r) * 136 + qoff + j * 16 + lcq] =
              f2bf(__expf(sacc[i][j][r]));
    __syncthreads();                      // p complete

    // ---- PV: oac[k][c] += p @ h''^T (wave: 64k x 32c; B from L2) ----
    #pragma unroll
    for (int cs = 0; cs < 4; ++cs) {
      bf16x8 a2[4], b2[2];
      #pragma unroll
      for (int j = 0; j < 2; ++j)
        b2[j] = *(const bf16x8*)
            &Hbase[(size_t)(coff + j * 16 + lcq) * Q_ + qc * 128 + cs * 32 + lrq * 8];
      #pragma unroll
      for (int i = 0; i < 4; ++i)
        a2[i] = *(const bf16x8*)&Fa[(koff + i * 16 + lcq) * 136 + cs * 32 + lrq * 8];
      #pragma unroll
      for (int i = 0; i < 4; ++i)
        #pragma unroll
        for (int j = 0; j < 2; ++j)
          oac[i][j] = MFMA(a2[i], b2[j], oac[i][j]);
    }
    __syncthreads();                      // p reads done

    if (qc < 7) {
      STAGE_F(qc + 1);
      __syncthreads();                    // next F staged
    }
  }

  // ---- epilogue: o1T via transpose tile (overlays smem) ----
  unsigned short* ot = (unsigned short*)smem;   // [128][132]
  #pragma unroll
  for (int i = 0; i < 4; ++i)
    #pragma unroll
    for (int j = 0; j < 2; ++j)
      #pragma unroll
      for (int r = 0; r < 4; ++r)
        ot[(koff + i * 16 + lrq * 4 + r) * 132 + coff + j * 16 + lcq] =
            f2bf(oac[i][j][r]);
  __syncthreads();
  const int row = t >> 2, chunk = (t & 3) * 32;
  unsigned short* dst = &o1T[((size_t)(b * W_ + k0 + row)) * C2 + cy * 128 + chunk];
  #pragma unroll
  for (int u = 0; u < 4; ++u)
    *(uint4*)&dst[u * 8] = *(uint4*)&ot[row * 132 + chunk + u * 8];
}

// ---------------------------------------------------------------------------
// K4 v3: out = gamma*(o1T @ wa^T + ba) + x.  Staged + conflict-free swizzle.
// grid (16,4,16), 256 thr.
// ---------------------------------------------------------------------------
__global__ __launch_bounds__(256)
void k_out(const unsigned short* __restrict__ o1T, const unsigned short* __restrict__ wabf,
           const float* __restrict__ ba, const float* __restrict__ x,
           const float* __restrict__ gamma, float* __restrict__ out)
{
  const int b = blockIdx.z, co0 = blockIdx.y * 128, w0 = blockIdx.x * 128;
  const int t = threadIdx.x, l = t & 63, wv = t >> 6;
  const int wr = wv >> 1, wc = wv & 1;

  __shared__ __align__(16) unsigned short stg[4][4096];   // 32 KB dbuf staging

  const unsigned short* Abase = o1T + (size_t)(b * W_ + w0) * C2;
  const unsigned short* Bbase = wabf + (size_t)co0 * C2;

  const int wub = (t & 192) * 8;
  const int r0s = t >> 2;
  const int kcs = ((t & 3) ^ ((t >> 3) & 3)) * 8;
  const int gsw = (((l >> 4) ^ ((l >> 1) & 3)) << 3);

  auto STAGE = [&](int buf, int c0) {
    #pragma unroll
    for (int i = 0; i < 2; ++i) {
      const int row = i * 64 + r0s;
      gload16(Abase + (size_t)row * C2 + c0 + kcs, &stg[buf * 2 + 0][i * 2048 + wub]);
      gload16(Bbase + (size_t)row * C2 + c0 + kcs, &stg[buf * 2 + 1][i * 2048 + wub]);
    }
  };

  f32x4 acc[4][4];
  #pragma unroll
  for (int i = 0; i < 4; ++i)
    #pragma unroll
    for (int j = 0; j < 4; ++j) acc[i][j] = (f32x4){0.f, 0.f, 0.f, 0.f};

  STAGE(0, 0);
  for (int kt = 0; kt < 8; ++kt) {
    const int cur = kt & 1;
    __syncthreads();
    if (kt + 1 < 8) STAGE(cur ^ 1, (kt + 1) * 32);
    const unsigned short* As = stg[cur * 2 + 0];
    const unsigned short* Bs = stg[cur * 2 + 1];
    bf16x8 a[4], bb[4];
    #pragma unroll
    for (int i = 0; i < 4; ++i)
      a[i] = *(const bf16x8*)&As[(wr * 64 + i * 16 + (l & 15)) * 32 + gsw];
    #pragma unroll
    for (int j = 0; j < 4; ++j)
      bb[j] = *(const bf16x8*)&Bs[(wc * 64 + j * 16 + (l & 15)) * 32 + gsw];
    #pragma unroll
    for (int i = 0; i < 4; ++i)
      #pragma unroll
      for (int j = 0; j < 4; ++j)
        acc[i][j] = MFMA(a[i], bb[j], acc[i][j]);
  }

  const float gm = gamma[0];
  const int lr = l >> 4, lc = l & 15;
  #pragma unroll
  for (int i = 0; i < 4; ++i)
    #pragma unroll
    for (int j = 0; j < 4; ++j) {
      const int co = co0 + wc * 64 + j * 16 + lc;
      const int w  = w0 + wr * 64 + i * 16 + lr * 4;
      const float bb2 = ba[co];
      const size_t idx = ((size_t)(b * C_ + co)) * W_ + w;
      const float4 xv = *(const float4*)&x[idx];
      float4 ov;
      ov.x = gm * (acc[i][j][0] + bb2) + xv.x;
      ov.y = gm * (acc[i][j][1] + bb2) + xv.y;
      ov.z = gm * (acc[i][j][2] + bb2) + xv.z;
      ov.w = gm * (acc[i][j][3] + bb2) + xv.w;
      *(float4*)&out[idx] = ov;
    }
}

// ---------------------------------------------------------------------------
extern "C" void kernel_launch(void* const* d_in, const int* in_sizes, int n_in,
                              void* d_out, int out_size, void* d_ws, size_t ws_size,
                              hipStream_t stream)
{
  const float* x     = (const float*)d_in[0];
  const float* wf    = (const float*)d_in[1];
  const float* bfp   = (const float*)d_in[2];
  const float* wg    = (const float*)d_in[3];
  const float* bgp   = (const float*)d_in[4];
  const float* wh    = (const float*)d_in[5];
  const float* bhp   = (const float*)d_in[6];
  const float* wa    = (const float*)d_in[7];
  const float* ba    = (const float*)d_in[8];
  const float* gamma = (const float*)d_in[9];
  float* out = (float*)d_out;

  unsigned short* ws = (unsigned short*)d_ws;
  size_t off = 0;
  unsigned short* wbf = ws + off;  off += 393216;
  unsigned short* xT  = ws + off;  off += (size_t)B_ * W_ * C_;      // 32 MB
  unsigned short* fT  = ws + off;  off += (size_t)B_ * Q_ * C4;      //  4 MB
  unsigned short* gT  = ws + off;  off += (size_t)B_ * W_ * C4;      //  8 MB
  unsigned short* h   = ws + off;  off += (size_t)B_ * C2 * Q_;      //  8 MB
  unsigned short* hpp = ws + off;  off += (size_t)B_ * C2 * Q_;      //  8 MB
  unsigned short* o1T = ws + off;  off += (size_t)B_ * W_ * C2;      // 16 MB
  float* lpart = (float*)(ws + off);  off += (size_t)16 * B_ * Q_ * 2; // 1 MB f32
  unsigned short* wabf = wbf + 262144;

  k_cvt<<<dim3(1536), dim3(256), 0, stream>>>(wf, wg, wh, wa, wbf);
  k_tx<<<dim3(W_ / 64, C_ / 64, B_), dim3(256), 0, stream>>>(x, xT);
  k_fgh<<<dim3(W_ / 128, 4, B_), dim3(256), 0, stream>>>(xT, wbf, bfp, bgp, bhp, fT, gT, h);
  k_stats<<<dim3(W_ / 128, Q_ / 128, B_), dim3(256), 0, stream>>>(fT, gT, lpart);
  k_hprime<<<dim3(Q_ / 128, B_), dim3(256), 0, stream>>>(h, lpart, hpp);
  k_o1f<<<dim3(W_ / 128, 2, B_), dim3(512), 0, stream>>>(fT, gT, hpp, o1T);
  k_out<<<dim3(W_ / 128, 4, B_), dim3(256), 0, stream>>>(o1T, wabf, ba, x, gamma, out);
}

// Round 14
// 171.851 us; speedup vs baseline: 1.1527x; 1.1527x over previous
//
#include <hip/hip_runtime.h>

#define DI __device__ __forceinline__

constexpr int B_ = 16;
constexpr int C_ = 512;
constexpr int W_ = 2048;
constexpr int C4 = 128;
constexpr int C2 = 256;
constexpr int Q_ = 1024;

typedef short bf16x8 __attribute__((ext_vector_type(8)));
typedef float f32x4 __attribute__((ext_vector_type(4)));

DI f32x4 MFMA(bf16x8 a, bf16x8 b, f32x4 c) {
  return __builtin_amdgcn_mfma_f32_16x16x32_bf16(a, b, c, 0, 0, 0);
}

DI unsigned short f2bf(float v) {
  union { float f; unsigned int i; } c; c.f = v;
  return (unsigned short)((c.i + 0x7FFFu + ((c.i >> 16) & 1u)) >> 16);
}

DI float bf16_to_f(unsigned short u) {
  union { unsigned int i; float f; } c; c.i = ((unsigned int)u) << 16; return c.f;
}

DI bf16x8 ldfrag(const unsigned short* p, int ld) {
  const int l = threadIdx.x & 63;
  return *(const bf16x8*)(p + (size_t)(l & 15) * ld + ((l >> 4) << 3));
}

// async 16B global->LDS; lds dest is wave-uniform base + lane*16
DI void gload16(const unsigned short* g, unsigned short* l) {
  __builtin_amdgcn_global_load_lds((const __attribute__((address_space(1))) void*)(g),
                                   (__attribute__((address_space(3))) void*)(l), 16, 0, 0);
}

// ---------------------------------------------------------------------------
// Prep 1: weights -> bf16.  [wf 64K][wg 64K][wh 128K][wa 128K]
// ---------------------------------------------------------------------------
__global__ __launch_bounds__(256)
void k_cvt(const float* __restrict__ wf, const float* __restrict__ wg,
           const float* __restrict__ wh, const float* __restrict__ wa,
           unsigned short* __restrict__ dst)
{
  const int i = blockIdx.x * 256 + threadIdx.x;
  float v;
  if (i < 65536)        v = wf[i];
  else if (i < 131072)  v = wg[i - 65536];
  else if (i < 262144)  v = wh[i - 131072];
  else                  v = wa[i - 262144];
  dst[i] = f2bf(v);
}

// ---------------------------------------------------------------------------
// Prep 2: xT[b][w][c] bf16 = transpose of x[b][c][w] f32.
// ---------------------------------------------------------------------------
__global__ __launch_bounds__(256)
void k_tx(const float* __restrict__ x, unsigned short* __restrict__ xT)
{
  __shared__ float tile[64][68];
  const int b = blockIdx.z, c0 = blockIdx.y * 64, w0 = blockIdx.x * 64;
  const int t = threadIdx.x;
  #pragma unroll
  for (int p = 0; p < 4; ++p) {
    const int r = p * 16 + (t >> 4);
    const float4 v = *(const float4*)&x[((size_t)(b * C_ + c0 + r)) * W_ + w0 + (t & 15) * 4];
    *(float4*)&tile[r][(t & 15) * 4] = v;
  }
  __syncthreads();
  const int w = t >> 2, ch = (t & 3) * 16;
  unsigned short o[16];
  #pragma unroll
  for (int j = 0; j < 16; ++j) o[j] = f2bf(tile[ch + j][w]);
  unsigned short* dst = &xT[((size_t)(b * W_ + w0 + w)) * C_ + c0 + ch];
  *(uint4*)&dst[0] = *(uint4*)&o[0];
  *(uint4*)&dst[8] = *(uint4*)&o[8];
}

// ---------------------------------------------------------------------------
// K1: m97-style LDS-staged GEMM, conflict-free XOR-swizzled staging.
// Tile 128(w) x 128(ch), BK=32, 4 waves 2x2. grid (16,4,16)
// ---------------------------------------------------------------------------
__global__ __launch_bounds__(256)
void k_fgh(const unsigned short* __restrict__ xT, const unsigned short* __restrict__ wcat,
           const float* __restrict__ bfp, const float* __restrict__ bgp,
           const float* __restrict__ bhp,
           unsigned short* __restrict__ fT, unsigned short* __restrict__ gT,
           unsigned short* __restrict__ h)
{
  const int b = blockIdx.z, rt = blockIdx.y, w0 = blockIdx.x * 128;
  const int t = threadIdx.x, l = t & 63, wv = t >> 6;
  const int wr = wv >> 1, wc = wv & 1;

  __shared__ __align__(16) char smraw[33792];   // staging 32KB | epilogue 64x132 f32
  unsigned short* stg = (unsigned short*)smraw; // [buf][ab][4096]
  float (*eps)[132] = (float(*)[132])smraw;

  const unsigned short* Abase = xT + ((size_t)(b * W_ + w0)) * C_;
  const unsigned short* Bbase = wcat + (size_t)(rt * 128) * C_;

  const int wub = (t & 192) * 8;
  const int r0s = t >> 2;
  const int kcs = ((t & 3) ^ ((t >> 3) & 3)) * 8;
  const int gsw = (((l >> 4) ^ ((l >> 1) & 3)) << 3);

  auto STAGE = [&](int buf, int c0) {
    #pragma unroll
    for (int i = 0; i < 2; ++i) {
      const int row = i * 64 + r0s;
      gload16(Abase + (size_t)row * C_ + c0 + kcs, stg + (buf * 2 + 0) * 4096 + i * 2048 + wub);
      gload16(Bbase + (size_t)row * C_ + c0 + kcs, stg + (buf * 2 + 1) * 4096 + i * 2048 + wub);
    }
  };

  f32x4 acc[4][4];
  #pragma unroll
  for (int i = 0; i < 4; ++i)
    #pragma unroll
    for (int j = 0; j < 4; ++j) acc[i][j] = (f32x4){0.f, 0.f, 0.f, 0.f};

  STAGE(0, 0);
  for (int kt = 0; kt < 16; ++kt) {
    const int cur = kt & 1;
    __syncthreads();
    if (kt + 1 < 16) STAGE(cur ^ 1, (kt + 1) * 32);
    const unsigned short* As = stg + (cur * 2 + 0) * 4096;
    const unsigned short* Bs = stg + (cur * 2 + 1) * 4096;
    bf16x8 a[4], bb[4];
    #pragma unroll
    for (int i = 0; i < 4; ++i)
      a[i] = *(const bf16x8*)&As[(wr * 64 + i * 16 + (l & 15)) * 32 + gsw];
    #pragma unroll
    for (int j = 0; j < 4; ++j)
      bb[j] = *(const bf16x8*)&Bs[(wc * 64 + j * 16 + (l & 15)) * 32 + gsw];
    #pragma unroll
    for (int i = 0; i < 4; ++i)
      #pragma unroll
      for (int j = 0; j < 4; ++j)
        acc[i][j] = MFMA(a[i], bb[j], acc[i][j]);
  }
  __syncthreads();

  const int lr = l >> 4, lc = l & 15;

  if (rt == 1) {
    #pragma unroll
    for (int p = 0; p < 2; ++p) {
      if (p) __syncthreads();
      if (wr == p) {
        #pragma unroll
        for (int i = 0; i < 4; ++i)
          #pragma unroll
          for (int j = 0; j < 4; ++j)
            #pragma unroll
            for (int r = 0; r < 4; ++r)
              eps[i * 16 + lr * 4 + r][wc * 64 + j * 16 + lc] = acc[i][j][r];
      }
      __syncthreads();
      const int row = t >> 2, chunk = (t & 3) * 32;
      unsigned short o[32];
      #pragma unroll
      for (int j2 = 0; j2 < 32; ++j2) o[j2] = f2bf(eps[row][chunk + j2] + bgp[chunk + j2]);
      unsigned short* dst = &gT[((size_t)(b * W_ + w0 + p * 64 + row)) * C4 + chunk];
      #pragma unroll
      for (int u = 0; u < 4; ++u) *(uint4*)&dst[u * 8] = *(uint4*)&o[u * 8];
    }
  } else {
    #pragma unroll
    for (int i = 0; i < 4; ++i)
      #pragma unroll
      for (int j = 0; j < 4; ++j)
        #pragma unroll
        for (int jj = 0; jj < 2; ++jj)
          eps[wr * 32 + i * 8 + lr * 2 + jj][wc * 64 + j * 16 + lc] =
              fmaxf(acc[i][j][2 * jj], acc[i][j][2 * jj + 1]);
    __syncthreads();
    if (rt == 0) {
      const int row = t >> 2, chunk = (t & 3) * 32;
      unsigned short o[32];
      #pragma unroll
      for (int j2 = 0; j2 < 32; ++j2) o[j2] = f2bf(eps[row][chunk + j2] + bfp[chunk + j2]);
      unsigned short* dst = &fT[((size_t)(b * Q_ + (w0 >> 1) + row)) * C4 + chunk];
      #pragma unroll
      for (int u = 0; u < 4; ++u) *(uint4*)&dst[u * 8] = *(uint4*)&o[u * 8];
    } else {
      const int ch = t >> 1, half = (t & 1) * 32;
      const float bv = bhp[(rt - 2) * 128 + ch];
      unsigned short o[32];
      #pragma unroll
      for (int qq = 0; qq < 32; ++qq) o[qq] = f2bf(eps[half + qq][ch] + bv);
      unsigned short* dst = &h[((size_t)(b * C2 + (rt - 2) * 128 + ch)) * Q_ + (w0 >> 1) + half];
      #pragma unroll
      for (int u = 0; u < 4; ++u) *(uint4*)&dst[u * 8] = *(uint4*)&o[u * 8];
    }
  }
}

// ---------------------------------------------------------------------------
// K2a: k_stats — lpart[kt][b][q] = sum over this k-tile of exp(s[q,k]).
// Conflict-free swizzled staging. grid (16,8,16)
// ---------------------------------------------------------------------------
__global__ __launch_bounds__(256)
void k_stats(const unsigned short* __restrict__ fT, const unsigned short* __restrict__ gT,
             float* __restrict__ lpart)
{
  const int kt = blockIdx.x, qt = blockIdx.y, b = blockIdx.z;
  const int t = threadIdx.x, l = t & 63, wv = t >> 6;
  const int wr = wv >> 1, wc = wv & 1;

  __shared__ __align__(16) char smraw[33792];
  unsigned short* stg = (unsigned short*)smraw;
  float* sred = (float*)smraw;

  const unsigned short* Abase = fT + ((size_t)(b * Q_ + qt * 128)) * C4;
  const unsigned short* Bbase = gT + ((size_t)(b * W_ + kt * 128)) * C4;

  const int wub = (t & 192) * 8;
  const int r0s = t >> 2;
  const int kcs = ((t & 3) ^ ((t >> 3) & 3)) * 8;
  const int gsw = (((l >> 4) ^ ((l >> 1) & 3)) << 3);

  auto STAGE = [&](int buf, int c0) {
    #pragma unroll
    for (int i = 0; i < 2; ++i) {
      const int row = i * 64 + r0s;
      gload16(Abase + (size_t)row * C4 + c0 + kcs, stg + (buf * 2 + 0) * 4096 + i * 2048 + wub);
      gload16(Bbase + (size_t)row * C4 + c0 + kcs, stg + (buf * 2 + 1) * 4096 + i * 2048 + wub);
    }
  };

  f32x4 acc[4][4];
  #pragma unroll
  for (int i = 0; i < 4; ++i)
    #pragma unroll
    for (int j = 0; j < 4; ++j) acc[i][j] = (f32x4){0.f, 0.f, 0.f, 0.f};

  STAGE(0, 0);
  for (int ks = 0; ks < 4; ++ks) {
    const int cur = ks & 1;
    __syncthreads();
    if (ks + 1 < 4) STAGE(cur ^ 1, (ks + 1) * 32);
    const unsigned short* As = stg + (cur * 2 + 0) * 4096;
    const unsigned short* Bs = stg + (cur * 2 + 1) * 4096;
    bf16x8 a[4], bb[4];
    #pragma unroll
    for (int i = 0; i < 4; ++i)
      a[i] = *(const bf16x8*)&As[(wr * 64 + i * 16 + (l & 15)) * 32 + gsw];
    #pragma unroll
    for (int j = 0; j < 4; ++j)
      bb[j] = *(const bf16x8*)&Bs[(wc * 64 + j * 16 + (l & 15)) * 32 + gsw];
    #pragma unroll
    for (int i = 0; i < 4; ++i)
      #pragma unroll
      for (int j = 0; j < 4; ++j)
        acc[i][j] = MFMA(a[i], bb[j], acc[i][j]);
  }
  __syncthreads();

  const int lr = l >> 4, lc = l & 15;
  float sv[4][4];
  #pragma unroll
  for (int i = 0; i < 4; ++i)
    #pragma unroll
    for (int r = 0; r < 4; ++r) {
      float s = 0.f;
      #pragma unroll
      for (int j = 0; j < 4; ++j) s += __expf(acc[i][j][r]);
      #pragma unroll
      for (int d = 1; d < 16; d <<= 1) s += __shfl_xor(s, d);
      sv[i][r] = s;
    }
  if (lc == 0) {
    #pragma unroll
    for (int i = 0; i < 4; ++i)
      #pragma unroll
      for (int r = 0; r < 4; ++r)
        sred[wc * 128 + wr * 64 + i * 16 + lr * 4 + r] = sv[i][r];
  }
  __syncthreads();
  if (t < 128)
    lpart[((size_t)(kt * 16 + b)) * Q_ + qt * 128 + t] = sred[t] + sred[128 + t];
}

// ---------------------------------------------------------------------------
// K2b: k_hprime — h''[c][q] = h[c][q] / l[q], l = sum of 16 lpart slices.
// grid (Q/128, B), 256 thr
// ---------------------------------------------------------------------------
__global__ __launch_bounds__(256)
void k_hprime(const unsigned short* __restrict__ h, const float* __restrict__ lpart,
              unsigned short* __restrict__ hpp)
{
  const int qb = blockIdx.x, b = blockIdx.y;
  const int t = threadIdx.x;
  __shared__ float linv[128];
  if (t < 128) {
    float s = 0.f;
    #pragma unroll
    for (int kt = 0; kt < 16; ++kt)
      s += lpart[((size_t)(kt * 16 + b)) * Q_ + qb * 128 + t];
    linv[t] = 1.f / s;
  }
  __syncthreads();
  const int q8 = (t & 15) * 8;
  for (int it = 0; it < 16; ++it) {
    const int c = it * 16 + (t >> 4);
    const size_t off = ((size_t)(b * C2 + c)) * Q_ + qb * 128 + q8;
    const bf16x8 v = *(const bf16x8*)&h[off];
    unsigned short o[8];
    #pragma unroll
    for (int e = 0; e < 8; ++e)
      o[e] = f2bf(bf16_to_f((unsigned short)v[e]) * linv[q8 + e]);
    *(uint4*)&hpp[off] = *(uint4*)o;
  }
}

// ---------------------------------------------------------------------------
// K3f (reverted to R12 best): fused o1T[k][c] = sum_q exp(sT[k][q])*h''[c][q].
// Per block: one 128-k tile x all 256 c; 8 q-chunks {sT MFMA -> p=exp -> PV}.
// 8 waves. Gt staged once (A-frags hoisted); Ft/p share one arena; Hq 64KB.
// grid (W/128, B), 512 thr, 133 KB LDS (1 block/CU, 256 blocks).
// ---------------------------------------------------------------------------
__global__ __launch_bounds__(512)
void k_o1f(const unsigned short* __restrict__ fT, const unsigned short* __restrict__ gT,
           const unsigned short* __restrict__ hpp, unsigned short* __restrict__ o1T)
{
  const int b = blockIdx.y, k0 = blockIdx.x * 128;
  const int t = threadIdx.x, l = t & 63, wv = t >> 6;
  const int lcq = l & 15, lrq = l >> 4;

  __shared__ __align__(16) char smem[133120];
  unsigned short* Gt = (unsigned short*)smem;            // [128][128] 32 KB
  unsigned short* Fa = (unsigned short*)(smem + 32768);  // Ft [128][128] / p [128][136]
  unsigned short* Hq = (unsigned short*)(smem + 67584);  // [256][128] 64 KB

  #pragma unroll
  for (int rd = 0; rd < 4; ++rd) {
    const int idx = rd * 512 + t, row = idx >> 4, g = idx & 15;
    gload16(gT + ((size_t)(b * W_ + k0 + row)) * C4 + ((g ^ (row & 15)) << 3), Gt + idx * 8);
  }
  auto STAGE_F = [&](int qc) {
    #pragma unroll
    for (int rd = 0; rd < 4; ++rd) {
      const int idx = rd * 512 + t, row = idx >> 4, g = idx & 15;
      gload16(fT + ((size_t)(b * Q_ + qc * 128 + row)) * C4 + ((g ^ (row & 15)) << 3),
              Fa + idx * 8);
    }
  };
  auto STAGE_H = [&](int qc) {
    #pragma unroll
    for (int rd = 0; rd < 8; ++rd) {
      const int idx = rd * 512 + t, row = idx >> 4, g = idx & 15;
      gload16(hpp + ((size_t)(b * C2 + row)) * Q_ + qc * 128 + ((g ^ (row & 15)) << 3),
              Hq + idx * 8);
    }
  };
  STAGE_F(0);
  STAGE_H(0);
  __syncthreads();

  const int koff = (wv >> 2) * 64;
  const int qoff = (wv & 3) * 32;
  const int coff = (wv & 3) * 64;

  bf16x8 agt[4][4];
  #pragma unroll
  for (int i = 0; i < 4; ++i)
    #pragma unroll
    for (int cs = 0; cs < 4; ++cs)
      agt[i][cs] = *(const bf16x8*)
          &Gt[(koff + i * 16 + lcq) * 128 + (((cs * 4 + lrq) ^ lcq) << 3)];

  f32x4 oac[4][4];
  #pragma unroll
  for (int i = 0; i < 4; ++i)
    #pragma unroll
    for (int j = 0; j < 4; ++j) oac[i][j] = (f32x4){0.f, 0.f, 0.f, 0.f};

  for (int qc = 0; qc < 8; ++qc) {
    f32x4 sacc[4][2];
    #pragma unroll
    for (int i = 0; i < 4; ++i)
      #pragma unroll
      for (int j = 0; j < 2; ++j) sacc[i][j] = (f32x4){0.f, 0.f, 0.f, 0.f};
    #pragma unroll
    for (int cs = 0; cs < 4; ++cs) {
      bf16x8 bq[2];
      #pragma unroll
      for (int j = 0; j < 2; ++j)
        bq[j] = *(const bf16x8*)
            &Fa[(qoff + j * 16 + lcq) * 128 + (((cs * 4 + lrq) ^ lcq) << 3)];
      #pragma unroll
      for (int i = 0; i < 4; ++i)
        #pragma unroll
        for (int j = 0; j < 2; ++j)
          sacc[i][j] = MFMA(agt[i][cs], bq[j], sacc[i][j]);
    }
    __syncthreads();

    #pragma unroll
    for (int i = 0; i < 4; ++i)
      #pragma unroll
      for (int j = 0; j < 2; ++j)
        #pragma unroll
        for (int r = 0; r < 4; ++r)
          Fa[(koff + i * 16 + lrq * 4 + r) * 136 + qoff + j * 16 + lcq] =
              f2bf(__expf(sacc[i][j][r]));
    __syncthreads();

    #pragma unroll
    for (int cs = 0; cs < 4; ++cs) {
      bf16x8 a2[4], b2[4];
      #pragma unroll
      for (int i = 0; i < 4; ++i)
        a2[i] = *(const bf16x8*)&Fa[(koff + i * 16 + lcq) * 136 + cs * 32 + lrq * 8];
      #pragma unroll
      for (int j = 0; j < 4; ++j)
        b2[j] = *(const bf16x8*)
            &Hq[(coff + j * 16 + lcq) * 128 + (((cs * 4 + lrq) ^ lcq) << 3)];
      #pragma unroll
      for (int i = 0; i < 4; ++i)
        #pragma unroll
        for (int j = 0; j < 4; ++j)
          oac[i][j] = MFMA(a2[i], b2[j], oac[i][j]);
    }
    __syncthreads();

    if (qc < 7) {
      STAGE_F(qc + 1);
      STAGE_H(qc + 1);
      __syncthreads();
    }
  }

  unsigned short* ot = (unsigned short*)smem;   // [128][264]
  #pragma unroll
  for (int i = 0; i < 4; ++i)
    #pragma unroll
    for (int j = 0; j < 4; ++j)
      #pragma unroll
      for (int r = 0; r < 4; ++r)
        ot[(koff + i * 16 + lrq * 4 + r) * 264 + coff + j * 16 + lcq] =
            f2bf(oac[i][j][r]);
  __syncthreads();
  const int row = t >> 2, chunk = (t & 3) * 64;
  unsigned short* dst = &o1T[((size_t)(b * W_ + k0 + row)) * C2 + chunk];
  #pragma unroll
  for (int u = 0; u < 8; ++u)
    *(uint4*)&dst[u * 8] = *(uint4*)&ot[row * 264 + chunk + u * 8];
}

// ---------------------------------------------------------------------------
// K4 v3: out = gamma*(o1T @ wa^T + ba) + x.  Staged + conflict-free swizzle.
// grid (16,4,16), 256 thr.
// ---------------------------------------------------------------------------
__global__ __launch_bounds__(256)
void k_out(const unsigned short* __restrict__ o1T, const unsigned short* __restrict__ wabf,
           const float* __restrict__ ba, const float* __restrict__ x,
           const float* __restrict__ gamma, float* __restrict__ out)
{
  const int b = blockIdx.z, co0 = blockIdx.y * 128, w0 = blockIdx.x * 128;
  const int t = threadIdx.x, l = t & 63, wv = t >> 6;
  const int wr = wv >> 1, wc = wv & 1;

  __shared__ __align__(16) unsigned short stg[4][4096];   // 32 KB dbuf staging

  const unsigned short* Abase = o1T + (size_t)(b * W_ + w0) * C2;
  const unsigned short* Bbase = wabf + (size_t)co0 * C2;

  const int wub = (t & 192) * 8;
  const int r0s = t >> 2;
  const int kcs = ((t & 3) ^ ((t >> 3) & 3)) * 8;
  const int gsw = (((l >> 4) ^ ((l >> 1) & 3)) << 3);

  auto STAGE = [&](int buf, int c0) {
    #pragma unroll
    for (int i = 0; i < 2; ++i) {
      const int row = i * 64 + r0s;
      gload16(Abase + (size_t)row * C2 + c0 + kcs, &stg[buf * 2 + 0][i * 2048 + wub]);
      gload16(Bbase + (size_t)row * C2 + c0 + kcs, &stg[buf * 2 + 1][i * 2048 + wub]);
    }
  };

  f32x4 acc[4][4];
  #pragma unroll
  for (int i = 0; i < 4; ++i)
    #pragma unroll
    for (int j = 0; j < 4; ++j) acc[i][j] = (f32x4){0.f, 0.f, 0.f, 0.f};

  STAGE(0, 0);
  for (int kt = 0; kt < 8; ++kt) {
    const int cur = kt & 1;
    __syncthreads();
    if (kt + 1 < 8) STAGE(cur ^ 1, (kt + 1) * 32);
    const unsigned short* As = stg[cur * 2 + 0];
    const unsigned short* Bs = stg[cur * 2 + 1];
    bf16x8 a[4], bb[4];
    #pragma unroll
    for (int i = 0; i < 4; ++i)
      a[i] = *(const bf16x8*)&As[(wr * 64 + i * 16 + (l & 15)) * 32 + gsw];
    #pragma unroll
    for (int j = 0; j < 4; ++j)
      bb[j] = *(const bf16x8*)&Bs[(wc * 64 + j * 16 + (l & 15)) * 32 + gsw];
    #pragma unroll
    for (int i = 0; i < 4; ++i)
      #pragma unroll
      for (int j = 0; j < 4; ++j)
        acc[i][j] = MFMA(a[i], bb[j], acc[i][j]);
  }

  const float gm = gamma[0];
  const int lr = l >> 4, lc = l & 15;
  #pragma unroll
  for (int i = 0; i < 4; ++i)
    #pragma unroll
    for (int j = 0; j < 4; ++j) {
      const int co = co0 + wc * 64 + j * 16 + lc;
      const int w  = w0 + wr * 64 + i * 16 + lr * 4;
      const float bb2 = ba[co];
      const size_t idx = ((size_t)(b * C_ + co)) * W_ + w;
      const float4 xv = *(const float4*)&x[idx];
      float4 ov;
      ov.x = gm * (acc[i][j][0] + bb2) + xv.x;
      ov.y = gm * (acc[i][j][1] + bb2) + xv.y;
      ov.z = gm * (acc[i][j][2] + bb2) + xv.z;
      ov.w = gm * (acc[i][j][3] + bb2) + xv.w;
      *(float4*)&out[idx] = ov;
    }
}

// ---------------------------------------------------------------------------
extern "C" void kernel_launch(void* const* d_in, const int* in_sizes, int n_in,
                              void* d_out, int out_size, void* d_ws, size_t ws_size,
                              hipStream_t stream)
{
  const float* x     = (const float*)d_in[0];
  const float* wf    = (const float*)d_in[1];
  const float* bfp   = (const float*)d_in[2];
  const float* wg    = (const float*)d_in[3];
  const float* bgp   = (const float*)d_in[4];
  const float* wh    = (const float*)d_in[5];
  const float* bhp   = (const float*)d_in[6];
  const float* wa    = (const float*)d_in[7];
  const float* ba    = (const float*)d_in[8];
  const float* gamma = (const float*)d_in[9];
  float* out = (float*)d_out;

  unsigned short* ws = (unsigned short*)d_ws;
  size_t off = 0;
  unsigned short* wbf = ws + off;  off += 393216;
  unsigned short* xT  = ws + off;  off += (size_t)B_ * W_ * C_;      // 32 MB
  unsigned short* fT  = ws + off;  off += (size_t)B_ * Q_ * C4;      //  4 MB
  unsigned short* gT  = ws + off;  off += (size_t)B_ * W_ * C4;      //  8 MB
  unsigned short* h   = ws + off;  off += (size_t)B_ * C2 * Q_;      //  8 MB
  unsigned short* hpp = ws + off;  off += (size_t)B_ * C2 * Q_;      //  8 MB
  unsigned short* o1T = ws + off;  off += (size_t)B_ * W_ * C2;      // 16 MB
  float* lpart = (float*)(ws + off);  off += (size_t)16 * B_ * Q_ * 2; // 1 MB f32
  unsigned short* wabf = wbf + 262144;

  k_cvt<<<dim3(1536), dim3(256), 0, stream>>>(wf, wg, wh, wa, wbf);
  k_tx<<<dim3(W_ / 64, C_ / 64, B_), dim3(256), 0, stream>>>(x, xT);
  k_fgh<<<dim3(W_ / 128, 4, B_), dim3(256), 0, stream>>>(xT, wbf, bfp, bgp, bhp, fT, gT, h);
  k_stats<<<dim3(W_ / 128, Q_ / 128, B_), dim3(256), 0, stream>>>(fT, gT, lpart);
  k_hprime<<<dim3(Q_ / 128, B_), dim3(256), 0, stream>>>(h, lpart, hpp);
  k_o1f<<<dim3(W_ / 128, B_), dim3(512), 0, stream>>>(fT, gT, hpp, o1T);
  k_out<<<dim3(W_ / 128, 4, B_), dim3(256), 0, stream>>>(o1T, wabf, ba, x, gamma, out);
}